// Round 1
// baseline (270.503 us; speedup 1.0000x reference)
//
#include <hip/hip_runtime.h>
#include <hip/hip_bf16.h>
#include <hip/hip_fp16.h>

#define EPS 1e-8f
#define PI_F 3.14159265358979323846f

typedef _Float16 half8 __attribute__((ext_vector_type(8)));
typedef _Float16 half4 __attribute__((ext_vector_type(4)));
typedef _Float16 half2t __attribute__((ext_vector_type(2)));
typedef float f32x4 __attribute__((ext_vector_type(4)));

__device__ __forceinline__ float gelu_exact(float v) {
    return 0.5f * v * (1.0f + erff(v * 0.70710678118654752f));
}

// ---------------------------------------------------------------------------
// Kernel 0: convert embed_w [256,512] fp32 -> column-permuted, transposed
// fp16 hi/lo pair Wth/Wtl [512 rows n][256 k].
// Row j -> original column: g=j>>7, jj=j&127, d=(g<<6)+(jj&63),
// col = jj<64 ? d : 256+d.  (So GEMM block g gets cols [64g,64g+64) and the
// matching theta cols [256+64g, ...).)
// ---------------------------------------------------------------------------
__global__ void convertW(const float* __restrict__ W,
                         _Float16* __restrict__ Wth, _Float16* __restrict__ Wtl) {
    int idx = blockIdx.x * 256 + threadIdx.x;   // 0..131071
    int j = idx >> 8, k = idx & 255;
    int g = j >> 7, jj = j & 127;
    int d = (g << 6) + (jj & 63);
    int col = (jj < 64) ? d : (256 + d);
    float f = W[k * 512 + col];
    _Float16 h = (_Float16)f;
    Wth[idx] = h;
    Wtl[idx] = (_Float16)(f - (float)h);
}

// ---------------------------------------------------------------------------
// Kernel 1: embed GEMM (fp16x2 split, 3 MFMAs per frag) fused with polar
// transform. h = x@W+b;  r=|h1|+0.1; th=pi*h2; xc=r*cos(th); yc=r*sin(th).
// Stores XC,YC fp16 and atomically accumulates fp32 column sums (-> means).
// Tile: 128 M x 128 N (=64 d-pairs). 4 waves, each 32 rows x 128 cols.
// LDS XOR swizzle: chunk pos = c ^ ((row>>1)&3)  => <=2-way bank alias (free).
// ---------------------------------------------------------------------------
__global__ __launch_bounds__(256) void gemm_embed(
    const float* __restrict__ x,
    const _Float16* __restrict__ Wth, const _Float16* __restrict__ Wtl,
    const float* __restrict__ bias,
    _Float16* __restrict__ XC, _Float16* __restrict__ YC,
    float* __restrict__ XMsum, float* __restrict__ YMsum)
{
    __shared__ __attribute__((aligned(16))) _Float16 Ah[4096], Al[4096], Bh[4096], Bl[4096];
    const int tid  = threadIdx.x;
    const int wave = tid >> 6;
    const int lane = tid & 63;
    const int m0   = blockIdx.x * 128;
    const int g    = blockIdx.y;          // 0..3 : d-range [64g, 64g+64)
    const int q    = lane >> 4, ln = lane & 15;

    f32x4 acc[2][8];
#pragma unroll
    for (int mi = 0; mi < 2; ++mi)
#pragma unroll
        for (int nj = 0; nj < 8; ++nj)
            acc[mi][nj] = (f32x4){0.f, 0.f, 0.f, 0.f};

    for (int kt = 0; kt < 8; ++kt) {
        __syncthreads();
        // ---- stage B tiles [128 n][32 k] hi/lo (fp16, pre-converted) ----
#pragma unroll
        for (int c2 = 0; c2 < 2; ++c2) {
            int idx = c2 * 256 + tid;
            int r = idx >> 2, c = idx & 3;
            size_t go = (size_t)(g * 128 + r) * 256 + kt * 32 + c * 8;
            half8 vh = *(const half8*)(Wth + go);
            half8 vl = *(const half8*)(Wtl + go);
            int pos = c ^ ((r >> 1) & 3);
            *(half8*)&Bh[r * 32 + pos * 8] = vh;
            *(half8*)&Bl[r * 32 + pos * 8] = vl;
        }
        // ---- stage A tile [128 m][32 k]: fp32 -> (hi,lo) fp16 ----
#pragma unroll
        for (int L = 0; L < 4; ++L) {
            int idx = L * 256 + tid;          // float4 index, contiguous
            int r = idx >> 3, c4 = idx & 7;
            const float4 f = *(const float4*)(x + (size_t)(m0 + r) * 256 + kt * 32 + c4 * 4);
            half4 hh, ll;
            hh[0] = (_Float16)f.x; ll[0] = (_Float16)(f.x - (float)hh[0]);
            hh[1] = (_Float16)f.y; ll[1] = (_Float16)(f.y - (float)hh[1]);
            hh[2] = (_Float16)f.z; ll[2] = (_Float16)(f.z - (float)hh[2]);
            hh[3] = (_Float16)f.w; ll[3] = (_Float16)(f.w - (float)hh[3]);
            int pos = (c4 >> 1) ^ ((r >> 1) & 3);
            int off = r * 32 + pos * 8 + (c4 & 1) * 4;
            *(half4*)&Ah[off] = hh;
            *(half4*)&Al[off] = ll;
        }
        __syncthreads();

        // ---- fragments ----
        half8 a0[2], a1[2], bhf[8], blf[8];
#pragma unroll
        for (int mi = 0; mi < 2; ++mi) {
            int row = wave * 32 + mi * 16 + ln;
            int off = row * 32 + (q ^ ((row >> 1) & 3)) * 8;
            a0[mi] = *(const half8*)&Ah[off];
            a1[mi] = *(const half8*)&Al[off];
        }
#pragma unroll
        for (int nj = 0; nj < 8; ++nj) {
            int rn = nj * 16 + ln;
            int off = rn * 32 + (q ^ ((rn >> 1) & 3)) * 8;
            bhf[nj] = *(const half8*)&Bh[off];
            blf[nj] = *(const half8*)&Bl[off];
        }
        // ---- 3 passes (hi*hi, hi*lo, lo*hi); 16 indep MFMAs between acc reuse
#pragma unroll
        for (int nj = 0; nj < 8; ++nj)
#pragma unroll
            for (int mi = 0; mi < 2; ++mi)
                acc[mi][nj] = __builtin_amdgcn_mfma_f32_16x16x32_f16(a0[mi], bhf[nj], acc[mi][nj], 0, 0, 0);
#pragma unroll
        for (int nj = 0; nj < 8; ++nj)
#pragma unroll
            for (int mi = 0; mi < 2; ++mi)
                acc[mi][nj] = __builtin_amdgcn_mfma_f32_16x16x32_f16(a0[mi], blf[nj], acc[mi][nj], 0, 0, 0);
#pragma unroll
        for (int nj = 0; nj < 8; ++nj)
#pragma unroll
            for (int mi = 0; mi < 2; ++mi)
                acc[mi][nj] = __builtin_amdgcn_mfma_f32_16x16x32_f16(a1[mi], bhf[nj], acc[mi][nj], 0, 0, 0);
    }

    // ---- epilogue: pair col j (r-part) with col j+64 (theta-part) ----
    // C/D layout: col = lane&15, row = (lane>>4)*4 + reg   [m89 verified]
    const int b = m0 >> 10;   // 128-row tile lies within one batch b
#pragma unroll
    for (int nj = 0; nj < 4; ++nj) {
        const int d  = g * 64 + nj * 16 + ln;
        const float b1 = bias[d];
        const float b2 = bias[256 + d];
        float sx = 0.f, sy = 0.f;
#pragma unroll
        for (int mi = 0; mi < 2; ++mi) {
#pragma unroll
            for (int i = 0; i < 4; ++i) {
                const int row = m0 + wave * 32 + mi * 16 + q * 4 + i;
                const float h1 = acc[mi][nj][i] + b1;
                const float h2 = acc[mi][nj + 4][i] + b2;
                const float rr = fabsf(h1) + 0.1f;
                float sv, cv;
                __sincosf(PI_F * h2, &sv, &cv);
                const float xc = rr * cv, yc = rr * sv;
                XC[(size_t)row * 256 + d] = (_Float16)xc;
                YC[(size_t)row * 256 + d] = (_Float16)yc;
                sx += xc; sy += yc;
            }
        }
        // reduce over the 4 row-quads (lanes l, l+16, l+32, l+48 share d)
        sx += __shfl_down(sx, 32); sx += __shfl_down(sx, 16);
        sy += __shfl_down(sy, 32); sy += __shfl_down(sy, 16);
        if (lane < 16) {
            atomicAdd(&XMsum[b * 256 + d], sx);
            atomicAdd(&YMsum[b * 256 + d], sy);
        }
    }
}

// ---------------------------------------------------------------------------
// Kernel 2: the 8-layer recurrence on the means. One thread per (b,d).
// Key algebra: means propagate as xm += dx (broadcast adds), and all trig
// reduces to ratios: sin(atan2(y,x)) = y/hypot, cos(atan2(y,x)) = x/hypot.
// ---------------------------------------------------------------------------
__global__ __launch_bounds__(64) void layers_kernel(
    const float* __restrict__ XMsum, const float* __restrict__ YMsum,
    const float* __restrict__ mw1, const float* __restrict__ mb1,
    const float* __restrict__ mw2, const float* __restrict__ mb2,
    const float* __restrict__ pw1, const float* __restrict__ pb1,
    const float* __restrict__ pw2, const float* __restrict__ pb2,
    float* __restrict__ DX, float* __restrict__ DY)
{
    __shared__ float s_mw1[256], s_mb1[256], s_mw2[256], s_mb2[8];
    __shared__ float s_pw1[512], s_pb1[256], s_pw2[512], s_pb2[16];
    const int tid = threadIdx.x;
    for (int i = tid; i < 256; i += 64) { s_mw1[i] = mw1[i]; s_mb1[i] = mb1[i]; s_mw2[i] = mw2[i]; s_pb1[i] = pb1[i]; }
    for (int i = tid; i < 512; i += 64) { s_pw1[i] = pw1[i]; s_pw2[i] = pw2[i]; }
    if (tid < 8)  s_mb2[tid] = mb2[tid];
    if (tid < 16) s_pb2[tid] = pb2[tid];
    __syncthreads();

    const int idx = blockIdx.x * 64 + tid;    // (b,d) flat, 16384
    float xm = XMsum[idx] * (1.0f / 1024.0f);
    float ym = YMsum[idx] * (1.0f / 1024.0f);
    float dxa = 0.f, dya = 0.f;
#pragma unroll 1
    for (int i = 0; i < 8; ++i) {
        float r2    = xm * xm + ym * ym;
        float r_agg = sqrtf(r2 + EPS);
        float hyp   = sqrtf(r2);
        float inv   = hyp > 0.f ? 1.0f / hyp : 0.f;
        float st    = ym * inv;
        float ct    = hyp > 0.f ? xm * inv : 1.0f;   // atan2(0,0)=0 -> (0,1)
        float log_r = logf(r_agg + EPS);
        float lr = s_mb2[i];
#pragma unroll
        for (int k = 0; k < 32; ++k) {
            float h = gelu_exact(log_r * s_mw1[i * 32 + k] + s_mb1[i * 32 + k]);
            lr += h * s_mw2[i * 32 + k];
        }
        float r_trans = expf(lr);
        float p0 = s_pb2[i * 2 + 0], p1 = s_pb2[i * 2 + 1];
#pragma unroll
        for (int k = 0; k < 32; ++k) {
            float h = gelu_exact(st * s_pw1[i * 64 + k] + ct * s_pw1[i * 64 + 32 + k] + s_pb1[i * 32 + k]);
            p0 += h * s_pw2[i * 64 + 2 * k + 0];
            p1 += h * s_pw2[i * 64 + 2 * k + 1];
        }
        float hp   = sqrtf(p0 * p0 + p1 * p1);
        float invp = hp > 0.f ? 1.0f / hp : 0.f;
        float ctt  = hp > 0.f ? p1 * invp : 1.0f;
        float stt  = p0 * invp;
        float dx = r_trans * ctt;
        float dy = r_trans * stt;
        dxa += dx; dya += dy; xm += dx; ym += dy;
    }
    DX[idx] = dxa;
    DY[idx] = dya;
}

// ---------------------------------------------------------------------------
// Kernel 3: pooled[b,d] += sum_s sqrt((xc0+DX)^2 + (yc0+DY)^2 + EPS)
// grid (64 b, 8 s-chunks) x 256 thr; thread handles 2 d's (half2 loads).
// ---------------------------------------------------------------------------
__global__ __launch_bounds__(256) void pool_kernel(
    const _Float16* __restrict__ XC, const _Float16* __restrict__ YC,
    const float* __restrict__ DX, const float* __restrict__ DY,
    float* __restrict__ pooled)
{
    const int b = blockIdx.x, sc = blockIdx.y, tid = threadIdx.x;
    const int dp = (tid & 127) * 2;
    const int sh = tid >> 7;
    const float dx0 = DX[b * 256 + dp],     dy0 = DY[b * 256 + dp];
    const float dx1 = DX[b * 256 + dp + 1], dy1 = DY[b * 256 + dp + 1];
    size_t base = ((size_t)b * 1024 + sc * 128 + sh * 64) * 256 + dp;
    float s0 = 0.f, s1 = 0.f;
#pragma unroll 4
    for (int i = 0; i < 64; ++i) {
        half2t xc = *(const half2t*)(XC + base + (size_t)i * 256);
        half2t yc = *(const half2t*)(YC + base + (size_t)i * 256);
        float x0 = (float)xc[0] + dx0, y0 = (float)yc[0] + dy0;
        float x1 = (float)xc[1] + dx1, y1 = (float)yc[1] + dy1;
        s0 += sqrtf(x0 * x0 + y0 * y0 + EPS);
        s1 += sqrtf(x1 * x1 + y1 * y1 + EPS);
    }
    atomicAdd(&pooled[b * 256 + dp],     s0);
    atomicAdd(&pooled[b * 256 + dp + 1], s1);
}

// ---------------------------------------------------------------------------
// Kernel 4: classifier  gelu(pooled/1024 @ w1 + b1) @ w2 + b2  -> [64,1000]
// ---------------------------------------------------------------------------
__global__ __launch_bounds__(256) void cls_kernel(
    const float* __restrict__ pooled,
    const float* __restrict__ w1, const float* __restrict__ b1,
    const float* __restrict__ w2, const float* __restrict__ b2,
    float* __restrict__ out)
{
    __shared__ float pl[256];
    __shared__ float part[8][32];
    __shared__ float hd[32];
    const int b = blockIdx.x, tid = threadIdx.x;
    pl[tid] = pooled[b * 256 + tid] * (1.0f / 1024.0f);
    __syncthreads();
    const int hu = tid & 31, kc = tid >> 5;
    float a = 0.f;
    for (int k = kc * 32; k < kc * 32 + 32; ++k) a += pl[k] * w1[k * 32 + hu];
    part[kc][hu] = a;
    __syncthreads();
    if (tid < 32) {
        float s = b1[tid];
#pragma unroll
        for (int c = 0; c < 8; ++c) s += part[c][tid];
        hd[tid] = gelu_exact(s);
    }
    __syncthreads();
    for (int n = tid; n < 1000; n += 256) {
        float s = b2[n];
#pragma unroll
        for (int k = 0; k < 32; ++k) s += hd[k] * w2[k * 1000 + n];
        out[b * 1000 + n] = s;
    }
}

// ---------------------------------------------------------------------------
extern "C" void kernel_launch(void* const* d_in, const int* in_sizes, int n_in,
                              void* d_out, int out_size, void* d_ws, size_t ws_size,
                              hipStream_t stream)
{
    const float* x       = (const float*)d_in[0];
    const float* embed_w = (const float*)d_in[1];
    const float* embed_b = (const float*)d_in[2];
    const float* mag_w1  = (const float*)d_in[3];
    const float* mag_b1  = (const float*)d_in[4];
    const float* mag_w2  = (const float*)d_in[5];
    const float* mag_b2  = (const float*)d_in[6];
    const float* ph_w1   = (const float*)d_in[7];
    const float* ph_b1   = (const float*)d_in[8];
    const float* ph_w2   = (const float*)d_in[9];
    const float* ph_b2   = (const float*)d_in[10];
    const float* cls_w1  = (const float*)d_in[11];
    const float* cls_b1  = (const float*)d_in[12];
    const float* cls_w2  = (const float*)d_in[13];
    const float* cls_b2  = (const float*)d_in[14];
    float* out = (float*)d_out;

    char* ws = (char*)d_ws;
    // layout (bytes):
    _Float16* XC  = (_Float16*)(ws + 0);          // 33554432
    _Float16* YC  = (_Float16*)(ws + 33554432);   // 33554432
    _Float16* Wth = (_Float16*)(ws + 67108864);   // 262144
    _Float16* Wtl = (_Float16*)(ws + 67371008);   // 262144
    float* XMsum  = (float*)(ws + 67633152);      // 65536
    float* YMsum  = (float*)(ws + 67698688);      // 65536
    float* pooled = (float*)(ws + 67764224);      // 65536
    float* DX     = (float*)(ws + 67829760);      // 65536
    float* DY     = (float*)(ws + 67895296);      // 65536  (total ~64.8 MB)

    hipMemsetAsync(ws + 67633152, 0, 3 * 65536, stream);   // XMsum,YMsum,pooled

    convertW<<<512, 256, 0, stream>>>(embed_w, Wth, Wtl);
    gemm_embed<<<dim3(512, 4), 256, 0, stream>>>(x, Wth, Wtl, embed_b, XC, YC, XMsum, YMsum);
    layers_kernel<<<256, 64, 0, stream>>>(XMsum, YMsum, mag_w1, mag_b1, mag_w2, mag_b2,
                                          ph_w1, ph_b1, ph_w2, ph_b2, DX, DY);
    pool_kernel<<<dim3(64, 8), 256, 0, stream>>>(XC, YC, DX, DY, pooled);
    cls_kernel<<<64, 256, 0, stream>>>(pooled, cls_w1, cls_b1, cls_w2, cls_b2, out);
}

// Round 3
// 216.693 us; speedup vs baseline: 1.2483x; 1.2483x over previous
//
#include <hip/hip_runtime.h>
#include <hip/hip_bf16.h>
#include <hip/hip_fp16.h>

#define EPS 1e-8f
#define PI_F 3.14159265358979323846f

typedef _Float16 half8 __attribute__((ext_vector_type(8)));
typedef _Float16 half4 __attribute__((ext_vector_type(4)));
typedef float f32x4 __attribute__((ext_vector_type(4)));

__device__ __forceinline__ float gelu_exact(float v) {
    return 0.5f * v * (1.0f + erff(v * 0.70710678118654752f));
}

// ---------------------------------------------------------------------------
// Kernel 0: embed_w [256 k,512 col] fp32 -> permuted transposed fp16 hi/lo
// Wth/Wtl [512 j][256 k].  j = g*128 + (col<256 ? (col&63) : 64+(col&63)),
// g = (col%256)>>6.  Reads coalesced (col fast), writes scattered (small).
// ---------------------------------------------------------------------------
__global__ void convertW(const float* __restrict__ W,
                         _Float16* __restrict__ Wth, _Float16* __restrict__ Wtl) {
    int idx = blockIdx.x * 256 + threadIdx.x;   // 0..131071
    int col = idx & 511, k = idx >> 9;
    int d = col & 255, g = d >> 6;
    int j = g * 128 + ((col < 256) ? (d & 63) : (64 + (d & 63)));
    float f = W[k * 512 + col];
    _Float16 h = (_Float16)f;
    Wth[j * 256 + k] = h;
    Wtl[j * 256 + k] = (_Float16)(f - (float)h);
}

// ---------------------------------------------------------------------------
// Kernel 1: embed GEMM, 3-pass fp16 split (Ah*Bh + Ah*Bl + Al*Bh) -> fp32-
// grade h (R1-validated numerics; 2-pass failed at 0.203 > 0.166).
// Fused polar transform. Tile 128m x 128n (=64 d-pairs). Wave w owns
// n-groups {w, w+4} (r-part + theta-part of the same 16 d's) for ALL 128 m.
// grid dim3(4 g, 512 mtile): g fastest => 4 g-blocks of one m-tile
// co-resident => x fetched from HBM once.
// ---------------------------------------------------------------------------
__global__ __launch_bounds__(256, 3) void gemm_embed(
    const float* __restrict__ x,
    const _Float16* __restrict__ Wth, const _Float16* __restrict__ Wtl,
    const float* __restrict__ bias,
    _Float16* __restrict__ XY,
    float* __restrict__ XMsum, float* __restrict__ YMsum)
{
    __shared__ __attribute__((aligned(16))) _Float16 Ah[4096], Al[4096], Bh[4096], Bl[4096];
    const int tid  = threadIdx.x;
    const int wave = tid >> 6;
    const int lane = tid & 63;
    const int g    = blockIdx.x;          // 0..3 : d-range [64g, 64g+64)
    const int m0   = blockIdx.y * 128;
    const int q    = lane >> 4, ln = lane & 15;

    f32x4 acc[8][2];
#pragma unroll
    for (int mi = 0; mi < 8; ++mi) {
        acc[mi][0] = (f32x4){0.f, 0.f, 0.f, 0.f};
        acc[mi][1] = (f32x4){0.f, 0.f, 0.f, 0.f};
    }

    for (int kt = 0; kt < 8; ++kt) {
        __syncthreads();
        // ---- stage B tiles [128 n][32 k] hi/lo (pre-converted fp16) ----
#pragma unroll
        for (int c2 = 0; c2 < 2; ++c2) {
            int idx = c2 * 256 + tid;
            int r = idx >> 2, c = idx & 3;
            size_t go = (size_t)(g * 128 + r) * 256 + kt * 32 + c * 8;
            half8 vh = *(const half8*)(Wth + go);
            half8 vl = *(const half8*)(Wtl + go);
            int pos = c ^ ((r >> 1) & 3);
            *(half8*)&Bh[r * 32 + pos * 8] = vh;
            *(half8*)&Bl[r * 32 + pos * 8] = vl;
        }
        // ---- stage A tile [128 m][32 k]: fp32 -> fp16 hi + lo residual ----
#pragma unroll
        for (int L = 0; L < 2; ++L) {
            int idx = L * 256 + tid;          // 8-float chunk index
            int r = idx >> 2, cq = idx & 3;
            const float* src = x + (size_t)(m0 + r) * 256 + kt * 32 + cq * 8;
            const float4 f0 = *(const float4*)(src);
            const float4 f1 = *(const float4*)(src + 4);
            half8 hh, ll;
            hh[0] = (_Float16)f0.x; ll[0] = (_Float16)(f0.x - (float)hh[0]);
            hh[1] = (_Float16)f0.y; ll[1] = (_Float16)(f0.y - (float)hh[1]);
            hh[2] = (_Float16)f0.z; ll[2] = (_Float16)(f0.z - (float)hh[2]);
            hh[3] = (_Float16)f0.w; ll[3] = (_Float16)(f0.w - (float)hh[3]);
            hh[4] = (_Float16)f1.x; ll[4] = (_Float16)(f1.x - (float)hh[4]);
            hh[5] = (_Float16)f1.y; ll[5] = (_Float16)(f1.y - (float)hh[5]);
            hh[6] = (_Float16)f1.z; ll[6] = (_Float16)(f1.z - (float)hh[6]);
            hh[7] = (_Float16)f1.w; ll[7] = (_Float16)(f1.w - (float)hh[7]);
            int pos = cq ^ ((r >> 1) & 3);
            *(half8*)&Ah[r * 32 + pos * 8] = hh;
            *(half8*)&Al[r * 32 + pos * 8] = ll;
        }
        __syncthreads();

        // ---- fragments + 3 MFMA passes ----
        half8 bh[2], bl[2];
#pragma unroll
        for (int t = 0; t < 2; ++t) {
            int rn = (t * 4 + wave) * 16 + ln;
            int off = rn * 32 + (q ^ ((rn >> 1) & 3)) * 8;
            bh[t] = *(const half8*)&Bh[off];
            bl[t] = *(const half8*)&Bl[off];
        }
#pragma unroll
        for (int mi = 0; mi < 8; ++mi) {
            int row = mi * 16 + ln;
            int off = row * 32 + (q ^ ((row >> 1) & 3)) * 8;
            half8 am = *(const half8*)&Ah[off];
            half8 alm = *(const half8*)&Al[off];
#pragma unroll
            for (int t = 0; t < 2; ++t) {
                acc[mi][t] = __builtin_amdgcn_mfma_f32_16x16x32_f16(am,  bh[t], acc[mi][t], 0, 0, 0);
                acc[mi][t] = __builtin_amdgcn_mfma_f32_16x16x32_f16(am,  bl[t], acc[mi][t], 0, 0, 0);
                acc[mi][t] = __builtin_amdgcn_mfma_f32_16x16x32_f16(alm, bh[t], acc[mi][t], 0, 0, 0);
            }
        }
    }

    // ---- epilogue: this wave owns d = g*64 + wave*16 + ln for all 128 rows
    // C/D layout: col = lane&15, row = (lane>>4)*4 + reg   [m89 verified]
    const int d  = g * 64 + wave * 16 + ln;
    const int b  = m0 >> 10;
    const float b1 = bias[d];
    const float b2 = bias[256 + d];
    float sx = 0.f, sy = 0.f;
    union { _Float16 h[2]; unsigned u; } pk;
#pragma unroll
    for (int mi = 0; mi < 8; ++mi) {
#pragma unroll
        for (int i = 0; i < 4; ++i) {
            const int row = m0 + mi * 16 + q * 4 + i;
            const float h1 = acc[mi][0][i] + b1;
            const float h2 = acc[mi][1][i] + b2;
            const float rr = fabsf(h1) + 0.1f;
            float sv, cv;
            __sincosf(PI_F * h2, &sv, &cv);
            const float xc = rr * cv, yc = rr * sv;
            pk.h[0] = (_Float16)xc; pk.h[1] = (_Float16)yc;
            *(unsigned*)(XY + (size_t)row * 512 + d * 2) = pk.u;
            sx += xc; sy += yc;
        }
    }
    sx += __shfl_down(sx, 32); sx += __shfl_down(sx, 16);
    sy += __shfl_down(sy, 32); sy += __shfl_down(sy, 16);
    if (lane < 16) {
        atomicAdd(&XMsum[b * 256 + d], sx);
        atomicAdd(&YMsum[b * 256 + d], sy);
    }
}

// ---------------------------------------------------------------------------
// Kernel 2: 8-layer recurrence on the means. 8 threads per (b,d), 4 k-units
// each, shfl_xor(1,2,4) reduction.
// ---------------------------------------------------------------------------
__global__ __launch_bounds__(256) void layers_kernel(
    const float* __restrict__ XMsum, const float* __restrict__ YMsum,
    const float* __restrict__ mw1, const float* __restrict__ mb1,
    const float* __restrict__ mw2, const float* __restrict__ mb2,
    const float* __restrict__ pw1, const float* __restrict__ pb1,
    const float* __restrict__ pw2, const float* __restrict__ pb2,
    float* __restrict__ DX, float* __restrict__ DY)
{
    __shared__ float s_mw1[256], s_mb1[256], s_mw2[256], s_mb2[8];
    __shared__ float s_pw1[512], s_pb1[256], s_pw2[512], s_pb2[16];
    const int tid = threadIdx.x;
    s_mw1[tid] = mw1[tid]; s_mb1[tid] = mb1[tid];
    s_mw2[tid] = mw2[tid]; s_pb1[tid] = pb1[tid];
    s_pw1[tid] = pw1[tid]; s_pw1[256 + tid] = pw1[256 + tid];
    s_pw2[tid] = pw2[tid]; s_pw2[256 + tid] = pw2[256 + tid];
    if (tid < 8)  s_mb2[tid] = mb2[tid];
    if (tid < 16) s_pb2[tid] = pb2[tid];
    __syncthreads();

    const int gid = blockIdx.x * 256 + tid;
    const int idx = gid >> 3;                 // (b,d), 16384
    const int sub = gid & 7;                  // k-eighth
    float xm = XMsum[idx] * (1.0f / 1024.0f);
    float ym = YMsum[idx] * (1.0f / 1024.0f);
    float dxa = 0.f, dya = 0.f;
#pragma unroll 1
    for (int i = 0; i < 8; ++i) {
        float r2    = xm * xm + ym * ym;
        float r_agg = sqrtf(r2 + EPS);
        float hyp   = sqrtf(r2);
        float inv   = hyp > 0.f ? 1.0f / hyp : 0.f;
        float st    = ym * inv;
        float ct    = hyp > 0.f ? xm * inv : 1.0f;
        float log_r = logf(r_agg + EPS);
        float lr = 0.f, p0 = 0.f, p1 = 0.f;
#pragma unroll
        for (int k4 = 0; k4 < 4; ++k4) {
            int k = sub * 4 + k4;
            float hm = gelu_exact(log_r * s_mw1[i * 32 + k] + s_mb1[i * 32 + k]);
            lr += hm * s_mw2[i * 32 + k];
            float hp = gelu_exact(st * s_pw1[i * 64 + k] + ct * s_pw1[i * 64 + 32 + k] + s_pb1[i * 32 + k]);
            p0 += hp * s_pw2[i * 64 + 2 * k + 0];
            p1 += hp * s_pw2[i * 64 + 2 * k + 1];
        }
        lr += __shfl_xor(lr, 1); lr += __shfl_xor(lr, 2); lr += __shfl_xor(lr, 4);
        p0 += __shfl_xor(p0, 1); p0 += __shfl_xor(p0, 2); p0 += __shfl_xor(p0, 4);
        p1 += __shfl_xor(p1, 1); p1 += __shfl_xor(p1, 2); p1 += __shfl_xor(p1, 4);
        lr += s_mb2[i];
        p0 += s_pb2[i * 2 + 0];
        p1 += s_pb2[i * 2 + 1];
        float r_trans = expf(lr);
        float hp2  = sqrtf(p0 * p0 + p1 * p1);
        float invp = hp2 > 0.f ? 1.0f / hp2 : 0.f;
        float ctt  = hp2 > 0.f ? p1 * invp : 1.0f;
        float stt  = p0 * invp;
        float dx = r_trans * ctt;
        float dy = r_trans * stt;
        dxa += dx; dya += dy; xm += dx; ym += dy;
    }
    if (sub == 0) { DX[idx] = dxa; DY[idx] = dya; }
}

// ---------------------------------------------------------------------------
// Kernel 3: pooled[b,d] += sum_s sqrt((xc+DX)^2 + (yc+DY)^2 + EPS)
// XY interleaved (xc,yc) half pairs; 16B loads = 4 d's per thread.
// Block-level LDS reduction over the 4 s-subgroups, then 1 atomic per d.
// ---------------------------------------------------------------------------
__global__ __launch_bounds__(256) void pool_kernel(
    const _Float16* __restrict__ XY,
    const float* __restrict__ DX, const float* __restrict__ DY,
    float* __restrict__ pooled)
{
    __shared__ float red[256][4];
    const int b = blockIdx.x, sc = blockIdx.y, tid = threadIdx.x;
    const int dg = tid & 63;           // d-group: d = dg*4 .. dg*4+3
    const int sh = tid >> 6;           // s-subchunk (32 rows each)
    const int d = dg * 4;
    float dxv[4], dyv[4], s[4];
#pragma unroll
    for (int j = 0; j < 4; ++j) {
        dxv[j] = DX[b * 256 + d + j];
        dyv[j] = DY[b * 256 + d + j];
        s[j] = 0.f;
    }
    const int r0 = sc * 128 + sh * 32;
    const size_t base = ((size_t)b * 1024 + r0) * 512 + d * 2;
#pragma unroll 4
    for (int i = 0; i < 32; ++i) {
        half8 v = *(const half8*)(XY + base + (size_t)i * 512);
#pragma unroll
        for (int j = 0; j < 4; ++j) {
            float xv = (float)v[2 * j] + dxv[j];
            float yv = (float)v[2 * j + 1] + dyv[j];
            s[j] += sqrtf(xv * xv + yv * yv + EPS);
        }
    }
#pragma unroll
    for (int j = 0; j < 4; ++j) red[tid][j] = s[j];
    __syncthreads();
    if (tid < 64) {
#pragma unroll
        for (int j = 0; j < 4; ++j) {
            float t = red[tid][j] + red[tid + 64][j] + red[tid + 128][j] + red[tid + 192][j];
            atomicAdd(&pooled[b * 256 + tid * 4 + j], t);
        }
    }
}

// ---------------------------------------------------------------------------
// Kernel 4: classifier  gelu(pooled/1024 @ w1 + b1) @ w2 + b2  -> [64,1000]
// ---------------------------------------------------------------------------
__global__ __launch_bounds__(256) void cls_kernel(
    const float* __restrict__ pooled,
    const float* __restrict__ w1, const float* __restrict__ b1,
    const float* __restrict__ w2, const float* __restrict__ b2,
    float* __restrict__ out)
{
    __shared__ float pl[256];
    __shared__ float part[8][32];
    __shared__ float hd[32];
    const int b = blockIdx.x, tid = threadIdx.x;
    pl[tid] = pooled[b * 256 + tid] * (1.0f / 1024.0f);
    __syncthreads();
    const int hu = tid & 31, kc = tid >> 5;
    float a = 0.f;
    for (int k = kc * 32; k < kc * 32 + 32; ++k) a += pl[k] * w1[k * 32 + hu];
    part[kc][hu] = a;
    __syncthreads();
    if (tid < 32) {
        float s = b1[tid];
#pragma unroll
        for (int c = 0; c < 8; ++c) s += part[c][tid];
        hd[tid] = gelu_exact(s);
    }
    __syncthreads();
    for (int n = tid; n < 1000; n += 256) {
        float s = b2[n];
#pragma unroll
        for (int k = 0; k < 32; ++k) s += hd[k] * w2[k * 1000 + n];
        out[b * 1000 + n] = s;
    }
}

// ---------------------------------------------------------------------------
extern "C" void kernel_launch(void* const* d_in, const int* in_sizes, int n_in,
                              void* d_out, int out_size, void* d_ws, size_t ws_size,
                              hipStream_t stream)
{
    const float* x       = (const float*)d_in[0];
    const float* embed_w = (const float*)d_in[1];
    const float* embed_b = (const float*)d_in[2];
    const float* mag_w1  = (const float*)d_in[3];
    const float* mag_b1  = (const float*)d_in[4];
    const float* mag_w2  = (const float*)d_in[5];
    const float* mag_b2  = (const float*)d_in[6];
    const float* ph_w1   = (const float*)d_in[7];
    const float* ph_b1   = (const float*)d_in[8];
    const float* ph_w2   = (const float*)d_in[9];
    const float* ph_b2   = (const float*)d_in[10];
    const float* cls_w1  = (const float*)d_in[11];
    const float* cls_b1  = (const float*)d_in[12];
    const float* cls_w2  = (const float*)d_in[13];
    const float* cls_b2  = (const float*)d_in[14];
    float* out = (float*)d_out;

    char* ws = (char*)d_ws;
    _Float16* XY  = (_Float16*)(ws + 0);          // 67108864 B
    _Float16* Wth = (_Float16*)(ws + 67108864);   // 262144
    _Float16* Wtl = (_Float16*)(ws + 67371008);   // 262144
    float* XMsum  = (float*)(ws + 67633152);      // 65536
    float* YMsum  = (float*)(ws + 67698688);      // 65536
    float* pooled = (float*)(ws + 67764224);      // 65536
    float* DX     = (float*)(ws + 67829760);      // 65536
    float* DY     = (float*)(ws + 67895296);      // 65536

    hipMemsetAsync(ws + 67633152, 0, 3 * 65536, stream);   // XMsum,YMsum,pooled

    convertW<<<512, 256, 0, stream>>>(embed_w, Wth, Wtl);
    gemm_embed<<<dim3(4, 512), 256, 0, stream>>>(x, Wth, Wtl, embed_b, XY, XMsum, YMsum);
    layers_kernel<<<512, 256, 0, stream>>>(XMsum, YMsum, mag_w1, mag_b1, mag_w2, mag_b2,
                                           ph_w1, ph_b1, ph_w2, ph_b2, DX, DY);
    pool_kernel<<<dim3(64, 8), 256, 0, stream>>>(XY, DX, DY, pooled);
    cls_kernel<<<64, 256, 0, stream>>>(pooled, cls_w1, cls_b1, cls_w2, cls_b2, out);
}

// Round 4
// 213.087 us; speedup vs baseline: 1.2694x; 1.0169x over previous
//
#include <hip/hip_runtime.h>
#include <hip/hip_bf16.h>
#include <hip/hip_fp16.h>

#define EPS 1e-8f
#define PI_F 3.14159265358979323846f

typedef _Float16 half8 __attribute__((ext_vector_type(8)));
typedef _Float16 half4 __attribute__((ext_vector_type(4)));
typedef float f32x4 __attribute__((ext_vector_type(4)));
typedef float f32x2 __attribute__((ext_vector_type(2)));

__device__ __forceinline__ float gelu_exact(float v) {
    return 0.5f * v * (1.0f + erff(v * 0.70710678118654752f));
}

// ---------------------------------------------------------------------------
// Kernel 0: embed_w [256 k,512 col] fp32 -> permuted transposed fp16 hi/lo
// Wth/Wtl [512 j][256 k]. Also zero-inits XMsum/YMsum/pooled (replaces the
// separate hipMemsetAsync dispatch).
// ---------------------------------------------------------------------------
__global__ void convertW(const float* __restrict__ W,
                         _Float16* __restrict__ Wth, _Float16* __restrict__ Wtl,
                         float* __restrict__ zero_base) {
    int idx = blockIdx.x * 256 + threadIdx.x;   // 0..131071
    if (idx < 49152) zero_base[idx] = 0.f;      // XMsum,YMsum,pooled
    int col = idx & 511, k = idx >> 9;
    int d = col & 255, g = d >> 6;
    int j = g * 128 + ((col < 256) ? (d & 63) : (64 + (d & 63)));
    float f = W[k * 512 + col];
    _Float16 h = (_Float16)f;
    Wth[j * 256 + k] = h;
    Wtl[j * 256 + k] = (_Float16)(f - (float)h);
}

// ---------------------------------------------------------------------------
// Kernel 1: embed GEMM, 3-pass fp16 split (Ah*Bh + Ah*Bl + Al*Bh), fused
// polar transform. Tile 128m x 128n (64 d-pairs), wave w owns n-groups
// {w, w+4} for all 128 m.
// XCD swizzle: round-robin dispatch maps block id%8 -> XCD. We assign
// xcd=id&7, s=id>>3, g=s&3, mt=(s>>2)*8+xcd  => the 4 g-blocks of one
// m-tile share an XCD (ids 8 apart, co-resident) => x fetched once.
// XY stored as packed fp8 e4m3 pairs (pool path tolerates coarse storage;
// the amplified mean path stays fp32 in-register).
// ---------------------------------------------------------------------------
__global__ __launch_bounds__(256, 4) void gemm_embed(
    const float* __restrict__ x,
    const _Float16* __restrict__ Wth, const _Float16* __restrict__ Wtl,
    const float* __restrict__ bias,
    unsigned short* __restrict__ XY8,
    float* __restrict__ XMsum, float* __restrict__ YMsum)
{
    __shared__ __attribute__((aligned(16))) _Float16 Ah[4096], Al[4096], Bh[4096], Bl[4096];
    const int tid  = threadIdx.x;
    const int wave = tid >> 6;
    const int lane = tid & 63;
    const int id   = blockIdx.x;
    const int xcd  = id & 7;
    const int s    = id >> 3;
    const int g    = s & 3;                  // d-range [64g, 64g+64)
    const int mt   = (s >> 2) * 8 + xcd;     // 0..511
    const int m0   = mt * 128;
    const int q    = lane >> 4, ln = lane & 15;

    f32x4 acc[8][2];
#pragma unroll
    for (int mi = 0; mi < 8; ++mi) {
        acc[mi][0] = (f32x4){0.f, 0.f, 0.f, 0.f};
        acc[mi][1] = (f32x4){0.f, 0.f, 0.f, 0.f};
    }

    for (int kt = 0; kt < 8; ++kt) {
        __syncthreads();
        // ---- stage B tiles [128 n][32 k] hi/lo ----
#pragma unroll
        for (int c2 = 0; c2 < 2; ++c2) {
            int idx = c2 * 256 + tid;
            int r = idx >> 2, c = idx & 3;
            size_t go = (size_t)(g * 128 + r) * 256 + kt * 32 + c * 8;
            half8 vh = *(const half8*)(Wth + go);
            half8 vl = *(const half8*)(Wtl + go);
            int pos = c ^ ((r >> 1) & 3);
            *(half8*)&Bh[r * 32 + pos * 8] = vh;
            *(half8*)&Bl[r * 32 + pos * 8] = vl;
        }
        // ---- stage A tile [128 m][32 k]: fp32 -> fp16 hi + lo residual ----
#pragma unroll
        for (int L = 0; L < 2; ++L) {
            int idx = L * 256 + tid;
            int r = idx >> 2, cq = idx & 3;
            const float* src = x + (size_t)(m0 + r) * 256 + kt * 32 + cq * 8;
            const float4 f0 = *(const float4*)(src);
            const float4 f1 = *(const float4*)(src + 4);
            half8 hh, ll;
            hh[0] = (_Float16)f0.x; ll[0] = (_Float16)(f0.x - (float)hh[0]);
            hh[1] = (_Float16)f0.y; ll[1] = (_Float16)(f0.y - (float)hh[1]);
            hh[2] = (_Float16)f0.z; ll[2] = (_Float16)(f0.z - (float)hh[2]);
            hh[3] = (_Float16)f0.w; ll[3] = (_Float16)(f0.w - (float)hh[3]);
            hh[4] = (_Float16)f1.x; ll[4] = (_Float16)(f1.x - (float)hh[4]);
            hh[5] = (_Float16)f1.y; ll[5] = (_Float16)(f1.y - (float)hh[5]);
            hh[6] = (_Float16)f1.z; ll[6] = (_Float16)(f1.z - (float)hh[6]);
            hh[7] = (_Float16)f1.w; ll[7] = (_Float16)(f1.w - (float)hh[7]);
            int pos = cq ^ ((r >> 1) & 3);
            *(half8*)&Ah[r * 32 + pos * 8] = hh;
            *(half8*)&Al[r * 32 + pos * 8] = ll;
        }
        __syncthreads();

        // ---- fragments ----
        half8 bh[2], bl[2], am[8];
#pragma unroll
        for (int t = 0; t < 2; ++t) {
            int rn = (t * 4 + wave) * 16 + ln;
            int off = rn * 32 + (q ^ ((rn >> 1) & 3)) * 8;
            bh[t] = *(const half8*)&Bh[off];
            bl[t] = *(const half8*)&Bl[off];
        }
#pragma unroll
        for (int mi = 0; mi < 8; ++mi) {
            int row = mi * 16 + ln;
            am[mi] = *(const half8*)&Ah[row * 32 + (q ^ ((row >> 1) & 3)) * 8];
        }
        // pass 1: Ah*Bh (16 independent MFMAs)
#pragma unroll
        for (int mi = 0; mi < 8; ++mi)
#pragma unroll
            for (int t = 0; t < 2; ++t)
                acc[mi][t] = __builtin_amdgcn_mfma_f32_16x16x32_f16(am[mi], bh[t], acc[mi][t], 0, 0, 0);
        // pass 2: Ah*Bl
#pragma unroll
        for (int mi = 0; mi < 8; ++mi)
#pragma unroll
            for (int t = 0; t < 2; ++t)
                acc[mi][t] = __builtin_amdgcn_mfma_f32_16x16x32_f16(am[mi], bl[t], acc[mi][t], 0, 0, 0);
        // pass 3: Al*Bh
#pragma unroll
        for (int mi = 0; mi < 8; ++mi) {
            int row = mi * 16 + ln;
            half8 alv = *(const half8*)&Al[row * 32 + (q ^ ((row >> 1) & 3)) * 8];
#pragma unroll
            for (int t = 0; t < 2; ++t)
                acc[mi][t] = __builtin_amdgcn_mfma_f32_16x16x32_f16(alv, bh[t], acc[mi][t], 0, 0, 0);
        }
    }

    // ---- epilogue: wave owns d = g*64 + wave*16 + ln for all 128 rows ----
    // C/D layout: col = lane&15, row = (lane>>4)*4 + reg  [m89 verified]
    const int d  = g * 64 + wave * 16 + ln;
    const int b  = m0 >> 10;
    const float b1 = bias[d];
    const float b2 = bias[256 + d];
    float sx = 0.f, sy = 0.f;
#pragma unroll
    for (int mi = 0; mi < 8; ++mi) {
#pragma unroll
        for (int i = 0; i < 4; ++i) {
            const int row = m0 + mi * 16 + q * 4 + i;
            const float h1 = acc[mi][0][i] + b1;
            const float h2 = acc[mi][1][i] + b2;
            const float rr = fabsf(h1) + 0.1f;
            float sv, cv;
            __sincosf(PI_F * h2, &sv, &cv);
            const float xc = rr * cv, yc = rr * sv;
            int pk = __builtin_amdgcn_cvt_pk_fp8_f32(xc, yc, 0, false);
            XY8[(size_t)row * 256 + d] = (unsigned short)pk;
            sx += xc; sy += yc;    // mean path stays full fp32
        }
    }
    sx += __shfl_down(sx, 32); sx += __shfl_down(sx, 16);
    sy += __shfl_down(sy, 32); sy += __shfl_down(sy, 16);
    if (lane < 16) {
        atomicAdd(&XMsum[b * 256 + d], sx);
        atomicAdd(&YMsum[b * 256 + d], sy);
    }
}

// ---------------------------------------------------------------------------
// Kernel 2: 8-layer recurrence on the means. 8 threads per (b,d), 4 k-units
// each, shfl_xor(1,2,4) reduction.
// ---------------------------------------------------------------------------
__global__ __launch_bounds__(256) void layers_kernel(
    const float* __restrict__ XMsum, const float* __restrict__ YMsum,
    const float* __restrict__ mw1, const float* __restrict__ mb1,
    const float* __restrict__ mw2, const float* __restrict__ mb2,
    const float* __restrict__ pw1, const float* __restrict__ pb1,
    const float* __restrict__ pw2, const float* __restrict__ pb2,
    float* __restrict__ DX, float* __restrict__ DY)
{
    __shared__ float s_mw1[256], s_mb1[256], s_mw2[256], s_mb2[8];
    __shared__ float s_pw1[512], s_pb1[256], s_pw2[512], s_pb2[16];
    const int tid = threadIdx.x;
    s_mw1[tid] = mw1[tid]; s_mb1[tid] = mb1[tid];
    s_mw2[tid] = mw2[tid]; s_pb1[tid] = pb1[tid];
    s_pw1[tid] = pw1[tid]; s_pw1[256 + tid] = pw1[256 + tid];
    s_pw2[tid] = pw2[tid]; s_pw2[256 + tid] = pw2[256 + tid];
    if (tid < 8)  s_mb2[tid] = mb2[tid];
    if (tid < 16) s_pb2[tid] = pb2[tid];
    __syncthreads();

    const int gid = blockIdx.x * 256 + tid;
    const int idx = gid >> 3;                 // (b,d), 16384
    const int sub = gid & 7;                  // k-eighth
    float xm = XMsum[idx] * (1.0f / 1024.0f);
    float ym = YMsum[idx] * (1.0f / 1024.0f);
    float dxa = 0.f, dya = 0.f;
#pragma unroll 1
    for (int i = 0; i < 8; ++i) {
        float r2    = xm * xm + ym * ym;
        float r_agg = sqrtf(r2 + EPS);
        float hyp   = sqrtf(r2);
        float inv   = hyp > 0.f ? 1.0f / hyp : 0.f;
        float st    = ym * inv;
        float ct    = hyp > 0.f ? xm * inv : 1.0f;
        float log_r = logf(r_agg + EPS);
        float lr = 0.f, p0 = 0.f, p1 = 0.f;
#pragma unroll
        for (int k4 = 0; k4 < 4; ++k4) {
            int k = sub * 4 + k4;
            float hm = gelu_exact(log_r * s_mw1[i * 32 + k] + s_mb1[i * 32 + k]);
            lr += hm * s_mw2[i * 32 + k];
            float hp = gelu_exact(st * s_pw1[i * 64 + k] + ct * s_pw1[i * 64 + 32 + k] + s_pb1[i * 32 + k]);
            p0 += hp * s_pw2[i * 64 + 2 * k + 0];
            p1 += hp * s_pw2[i * 64 + 2 * k + 1];
        }
        lr += __shfl_xor(lr, 1); lr += __shfl_xor(lr, 2); lr += __shfl_xor(lr, 4);
        p0 += __shfl_xor(p0, 1); p0 += __shfl_xor(p0, 2); p0 += __shfl_xor(p0, 4);
        p1 += __shfl_xor(p1, 1); p1 += __shfl_xor(p1, 2); p1 += __shfl_xor(p1, 4);
        lr += s_mb2[i];
        p0 += s_pb2[i * 2 + 0];
        p1 += s_pb2[i * 2 + 1];
        float r_trans = expf(lr);
        float hp2  = sqrtf(p0 * p0 + p1 * p1);
        float invp = hp2 > 0.f ? 1.0f / hp2 : 0.f;
        float ctt  = hp2 > 0.f ? p1 * invp : 1.0f;
        float stt  = p0 * invp;
        float dx = r_trans * ctt;
        float dy = r_trans * stt;
        dxa += dx; dya += dy; xm += dx; ym += dy;
    }
    if (sub == 0) { DX[idx] = dxa; DY[idx] = dya; }
}

// ---------------------------------------------------------------------------
// Kernel 3: pooled[b,d] += sum_s sqrt((xc+DX)^2 + (yc+DY)^2 + EPS)
// XY8 packed fp8 pairs; 16B loads = 8 d's per thread. LDS reduce over the
// 8 s-subgroups (pad 9 -> conflict-free), 1 atomic per d.
// ---------------------------------------------------------------------------
__global__ __launch_bounds__(256) void pool_kernel(
    const unsigned short* __restrict__ XY8,
    const float* __restrict__ DX, const float* __restrict__ DY,
    float* __restrict__ pooled)
{
    __shared__ float red[256][9];
    const int b = blockIdx.x, sc = blockIdx.y, tid = threadIdx.x;
    const int dg = tid & 31;           // d-group: d = dg*8 .. dg*8+7
    const int sh = tid >> 5;           // s-subchunk (16 rows each)
    const int d0 = dg * 8;
    float dxv[8], dyv[8], s[8];
#pragma unroll
    for (int j = 0; j < 8; ++j) {
        dxv[j] = DX[b * 256 + d0 + j];
        dyv[j] = DY[b * 256 + d0 + j];
        s[j] = 0.f;
    }
    const int r0 = sc * 128 + sh * 16;
    const size_t base = ((size_t)b * 1024 + r0) * 256 + d0;
#pragma unroll 4
    for (int i = 0; i < 16; ++i) {
        const int4 v = *(const int4*)(XY8 + base + (size_t)i * 256);
        const int wv[4] = {v.x, v.y, v.z, v.w};
#pragma unroll
        for (int w = 0; w < 4; ++w) {
            f32x2 pa = __builtin_amdgcn_cvt_pk_f32_fp8(wv[w], false);
            f32x2 pb = __builtin_amdgcn_cvt_pk_f32_fp8(wv[w], true);
            float xa = pa[0] + dxv[2 * w],     ya = pa[1] + dyv[2 * w];
            float xb = pb[0] + dxv[2 * w + 1], yb = pb[1] + dyv[2 * w + 1];
            s[2 * w]     += sqrtf(xa * xa + ya * ya + EPS);
            s[2 * w + 1] += sqrtf(xb * xb + yb * yb + EPS);
        }
    }
#pragma unroll
    for (int j = 0; j < 8; ++j) red[tid][j] = s[j];
    __syncthreads();
    if (tid < 32) {
#pragma unroll
        for (int j = 0; j < 8; ++j) {
            float t = 0.f;
#pragma unroll
            for (int c = 0; c < 8; ++c) t += red[c * 32 + tid][j];
            atomicAdd(&pooled[b * 256 + tid * 8 + j], t);
        }
    }
}

// ---------------------------------------------------------------------------
// Kernel 4: classifier  gelu(pooled/1024 @ w1 + b1) @ w2 + b2  -> [64,1000]
// ---------------------------------------------------------------------------
__global__ __launch_bounds__(256) void cls_kernel(
    const float* __restrict__ pooled,
    const float* __restrict__ w1, const float* __restrict__ b1,
    const float* __restrict__ w2, const float* __restrict__ b2,
    float* __restrict__ out)
{
    __shared__ float pl[256];
    __shared__ float part[8][32];
    __shared__ float hd[32];
    const int b = blockIdx.x, tid = threadIdx.x;
    pl[tid] = pooled[b * 256 + tid] * (1.0f / 1024.0f);
    __syncthreads();
    const int hu = tid & 31, kc = tid >> 5;
    float a = 0.f;
    for (int k = kc * 32; k < kc * 32 + 32; ++k) a += pl[k] * w1[k * 32 + hu];
    part[kc][hu] = a;
    __syncthreads();
    if (tid < 32) {
        float s = b1[tid];
#pragma unroll
        for (int c = 0; c < 8; ++c) s += part[c][tid];
        hd[tid] = gelu_exact(s);
    }
    __syncthreads();
    for (int n = tid; n < 1000; n += 256) {
        float s = b2[n];
#pragma unroll
        for (int k = 0; k < 32; ++k) s += hd[k] * w2[k * 1000 + n];
        out[b * 1000 + n] = s;
    }
}

// ---------------------------------------------------------------------------
extern "C" void kernel_launch(void* const* d_in, const int* in_sizes, int n_in,
                              void* d_out, int out_size, void* d_ws, size_t ws_size,
                              hipStream_t stream)
{
    const float* x       = (const float*)d_in[0];
    const float* embed_w = (const float*)d_in[1];
    const float* embed_b = (const float*)d_in[2];
    const float* mag_w1  = (const float*)d_in[3];
    const float* mag_b1  = (const float*)d_in[4];
    const float* mag_w2  = (const float*)d_in[5];
    const float* mag_b2  = (const float*)d_in[6];
    const float* ph_w1   = (const float*)d_in[7];
    const float* ph_b1   = (const float*)d_in[8];
    const float* ph_w2   = (const float*)d_in[9];
    const float* ph_b2   = (const float*)d_in[10];
    const float* cls_w1  = (const float*)d_in[11];
    const float* cls_b1  = (const float*)d_in[12];
    const float* cls_w2  = (const float*)d_in[13];
    const float* cls_b2  = (const float*)d_in[14];
    float* out = (float*)d_out;

    char* ws = (char*)d_ws;
    unsigned short* XY8 = (unsigned short*)(ws + 0);   // 33554432 B (fp8 pairs)
    _Float16* Wth = (_Float16*)(ws + 33554432);        // 262144
    _Float16* Wtl = (_Float16*)(ws + 33816576);        // 262144
    float* XMsum  = (float*)(ws + 34078720);           // 65536
    float* YMsum  = (float*)(ws + 34144256);           // 65536
    float* pooled = (float*)(ws + 34209792);           // 65536
    float* DX     = (float*)(ws + 34275328);           // 65536
    float* DY     = (float*)(ws + 34340864);           // 65536

    convertW<<<512, 256, 0, stream>>>(embed_w, Wth, Wtl, XMsum);  // zeros XMsum,YMsum,pooled (contiguous)
    gemm_embed<<<2048, 256, 0, stream>>>(x, Wth, Wtl, embed_b, XY8, XMsum, YMsum);
    layers_kernel<<<512, 256, 0, stream>>>(XMsum, YMsum, mag_w1, mag_b1, mag_w2, mag_b2,
                                           ph_w1, ph_b1, ph_w2, ph_b2, DX, DY);
    pool_kernel<<<dim3(64, 8), 256, 0, stream>>>(XY8, DX, DY, pooled);
    cls_kernel<<<64, 256, 0, stream>>>(pooled, cls_w1, cls_b1, cls_w2, cls_b2, out);
}